// Round 2
// baseline (130.675 us; speedup 1.0000x reference)
//
#include <hip/hip_runtime.h>

// DeformableConv2D round 6: PIXB=8 grid (occupancy) + launch_bounds(256,4) (ILP).
//
// Round-5 post-mortem: __launch_bounds__(256,6) cut VGPRs 64->40, serializing
// the phase-B gather pipeline (per-wave issue rate halved: Occ 2x but VALUBusy
// flat, dur 60->74us). This round keeps the 1568-block grid (6.1 blocks/CU,
// LDS 20.9 KB -> 7/CU possible) but restores the (256,4) bound so the compiler
// can hold ~64 VGPRs and keep all 32 phase-B gather loads in flight.
// Also removed the s_sa row-zeroing loop: MFMA D rows are independent per-row
// dot products; rows 8..15 are never stored, so garbage A rows are harmless.
//
// prep: offset weights -> f16 transposed [80][576]; conv weights -> f16.
// main: 1568 blocks x 256 thr (4 waves), 8 pixels/block.
//   A : offset conv as MFMA GEMM, A-frags gathered straight from global x
//       (per-lane predicated loads: lane rows m>=8 masked off). Waves split
//       the 5 N-tiles (wave 3 takes tiles 3 and 4). ZERO barriers.
//   A': coord/weight table, lane = sample (288 items / 256 thr).
//   B : per tap: 8 gathers + weighted sum + f16 pack -> s_sa[w], then 2 MFMAs.
//       Wave w only touches s_sa[w] => NO barriers in the tap loop.
// Barriers per block: 2.
//
// MFMA 16x16x32 f16 layouts (verified by earlier passing runs):
//   A-frag: lane holds A[m=lane&15][k=(lane>>4)*8+j]
//   B-frag: lane holds B[k=(lane>>4)*8+j][n=lane&15]   (B stored [n][k])
//   C/D  : col(n)=lane&15, row(m)=(lane>>4)*4+reg

#define NH 56
#define NW 56
#define NC 64
#define NDG 4
#define NK 9
#define NOFF 72
#define NOFFP 80
#define NF 64
#define KTOT 576
#define HWPIX 3136
#define NPIX 12544
#define PIXB 8

#define WS_OFFKT 0          // f16 [80][576]   = 92160 B
#define WS_WK    92160      // f16 [9][64][64] = 73728 B

typedef _Float16 half8   __attribute__((ext_vector_type(8)));
typedef float    floatx4 __attribute__((ext_vector_type(4)));

// ---------------- prep: weight conversion ----------------
__global__ __launch_bounds__(256)
void dcn_prep(const float* __restrict__ offk,   // [3,3,64,72] (kk,oc)
              const float* __restrict__ wk,     // [3,3,64,64] (k,f,c)
              _Float16* __restrict__ offkt,     // [80][576]   (oc,kk)
              _Float16* __restrict__ wkh)       // [9][64][64]
{
    const int i = blockIdx.x * 256 + threadIdx.x;
    if (i < NOFFP * KTOT) {
        const int oc = i / KTOT;
        const int kk = i - oc * KTOT;
        const float v = (oc < NOFF) ? offk[kk * NOFF + oc] : 0.0f;
        offkt[i] = (_Float16)v;
    }
    const int j = i - NOFFP * KTOT;
    if (j >= 0 && j < NK * NF * NC) wkh[j] = (_Float16)wk[j];
}

// ---------------- fused main ----------------
__global__ __launch_bounds__(256, 4)
void dcn_main(const float* __restrict__ x,        // [4,56,56,64]
              const _Float16* __restrict__ offkt, // [80][576]
              const float* __restrict__ offb,     // [72]
              const _Float16* __restrict__ wkh,   // [9][64][64]
              float* __restrict__ out)            // [12544][64]
{
    __shared__ float s_off[PIXB * NOFF];                    // 2.3 KB
    __shared__ __align__(16) float s_cww[PIXB * 36 * 4];    // 4.6 KB
    __shared__ __align__(16) int   s_cwi[PIXB * 36 * 4];    // 4.6 KB
    __shared__ __align__(16) _Float16 s_sa[4][16 * 72];     // 9.2 KB

    const int tid  = threadIdx.x;
    const int w    = tid >> 6;      // wave id: A = N-tile, B = group
    const int lane = tid & 63;
    const int m    = lane & 15;     // MFMA row / col index
    const int kq   = lane >> 4;     // MFMA k-quad

    const int pix0 = blockIdx.x * PIXB;
    const int pixm = pix0 + m;      // m>=PIXB: neighbor block's pixel, masked
    const int bm   = pixm / HWPIX;
    const int rrm  = pixm - bm * HWPIX;
    const int ohm  = rrm / NW;
    const int owm  = rrm - ohm * NW;
    const bool mval = (m < PIXB);
    const float* xbase = x + (size_t)(bm * HWPIX + ohm * NW + owm) * NC + kq * 8;

    // ---- phase A: offset conv GEMM, zero barriers ----
    const int oc0 = w * 16 + m;     // 0..63
    floatx4 acc0, acc1;
    { const float bv = offb[oc0]; acc0 = (floatx4){bv, bv, bv, bv}; }
    { const float bv = (w == 3 && m < 8) ? offb[64 + m] : 0.0f;
      acc1 = (floatx4){bv, bv, bv, bv}; }

    #pragma unroll
    for (int k = 0; k < NK; ++k) {
        const int ki = k / 3, kj = k - 3 * ki;
        const int ih = ohm + ki - 1, iw = owm + kj - 1;
        const bool vld = mval && ((unsigned)ih < NH) && ((unsigned)iw < NW);
        const float* ap = xbase + ((ki - 1) * NW + (kj - 1)) * NC;
        #pragma unroll
        for (int s = 0; s < 2; ++s) {
            float4 a0 = make_float4(0.f, 0.f, 0.f, 0.f), a1 = a0;
            if (vld) {
                a0 = *(const float4*)(ap + s * 32);
                a1 = *(const float4*)(ap + s * 32 + 4);
            }
            half8 af;
            af[0] = (_Float16)a0.x; af[1] = (_Float16)a0.y;
            af[2] = (_Float16)a0.z; af[3] = (_Float16)a0.w;
            af[4] = (_Float16)a1.x; af[5] = (_Float16)a1.y;
            af[6] = (_Float16)a1.z; af[7] = (_Float16)a1.w;
            const int kkb = k * 64 + s * 32 + kq * 8;
            const half8 bf0 = *(const half8*)&offkt[(size_t)oc0 * KTOT + kkb];
            acc0 = __builtin_amdgcn_mfma_f32_16x16x32_f16(af, bf0, acc0, 0, 0, 0);
            if (w == 3) {
                const half8 bf1 = *(const half8*)&offkt[(size_t)(64 + m) * KTOT + kkb];
                acc1 = __builtin_amdgcn_mfma_f32_16x16x32_f16(af, bf1, acc1, 0, 0, 0);
            }
        }
    }
    // D rows (kq*4+r) >= PIXB belong to the neighbor block: mask the store.
    if (kq < 2) {
        #pragma unroll
        for (int r = 0; r < 4; ++r)
            s_off[(kq * 4 + r) * NOFF + oc0] = acc0[r];
        if (w == 3 && m < 8) {
            #pragma unroll
            for (int r = 0; r < 4; ++r)
                s_off[(kq * 4 + r) * NOFF + 64 + m] = acc1[r];
        }
    }
    __syncthreads();

    // ---- phase A': coord/weight table, lane = sample ----
    for (int i = tid; i < PIXB * 36; i += 256) {
        const int p  = i / 36;
        const int kg = i - p * 36;              // k*NDG + g
        const int k  = kg >> 2;
        const int ki = k / 3, kj = k - 3 * ki;
        const int pix = pix0 + p;
        const int b   = pix / HWPIX;
        const int rr  = pix - b * HWPIX;
        const int oh  = rr / NW, ow = rr - (rr / NW) * NW;
        const float offy = s_off[p * NOFF + kg * 2 + 0];
        const float offx = s_off[p * NOFF + kg * 2 + 1];
        float yv = fminf(fmaxf((float)(oh + ki) + offy, 0.0f), 57.0f);
        float xv = fminf(fmaxf((float)(ow + kj) + offx, 0.0f), 57.0f);
        const float y0f = floorf(yv), x0f = floorf(xv);
        const int y0 = (int)y0f, x0 = (int)x0f;
        const int y1 = min(y0 + 1, 57), x1 = min(x0 + 1, 57);
        const float ly = yv - y0f,       lx = xv - x0f;
        const float hy = (float)y1 - yv, hx = (float)x1 - xv;
        const bool vy0 = (unsigned)(y0 - 1) < NH;
        const bool vy1 = (unsigned)(y1 - 1) < NH;
        const bool vx0 = (unsigned)(x0 - 1) < NW;
        const bool vx1 = (unsigned)(x1 - 1) < NW;
        const float w00 = (vy0 && vx0) ? hy * hx : 0.0f;
        const float w01 = (vy0 && vx1) ? hy * lx : 0.0f;
        const float w10 = (vy1 && vx0) ? ly * hx : 0.0f;
        const float w11 = (vy1 && vx1) ? ly * lx : 0.0f;
        const int y0c = min(max(y0 - 1, 0), NH - 1);
        const int y1c = min(max(y1 - 1, 0), NH - 1);
        const int x0c = min(max(x0 - 1, 0), NW - 1);
        const int x1c = min(max(x1 - 1, 0), NW - 1);
        const int bb = b * HWPIX;
        *(float4*)&s_cww[i * 4] = make_float4(w00, w01, w10, w11);
        *(int4*)&s_cwi[i * 4]   = make_int4((bb + y0c * NW + x0c) * NC,
                                            (bb + y0c * NW + x1c) * NC,
                                            (bb + y1c * NW + x0c) * NC,
                                            (bb + y1c * NW + x1c) * NC);
    }
    __syncthreads();

    // ---- phase B: sampling + grouped conv, zero barriers ----
    floatx4 accB = (floatx4){0.f, 0.f, 0.f, 0.f};
    _Float16* sa = &s_sa[w][0];
    #pragma unroll 1
    for (int k = 0; k < NK; ++k) {
        #pragma unroll
        for (int p = 0; p < PIXB; ++p) {
            const int i = (p * 36 + k * 4 + w) * 4;
            const float4 cw = *(const float4*)&s_cww[i];
            const int4  ci = *(const int4*)&s_cwi[i];
            float v =       cw.x * x[ci.x + lane];
            v = fmaf(cw.y, x[ci.y + lane], v);
            v = fmaf(cw.z, x[ci.z + lane], v);
            v = fmaf(cw.w, x[ci.w + lane], v);
            sa[p * 72 + lane] = (_Float16)v;
        }
        #pragma unroll
        for (int s = 0; s < 2; ++s) {
            const half8 af = *(const half8*)&sa[m * 72 + s * 32 + kq * 8];
            const half8 bf = *(const half8*)&wkh[(size_t)(k * NF + w * 16 + m) * NC +
                                                 s * 32 + kq * 8];
            accB = __builtin_amdgcn_mfma_f32_16x16x32_f16(af, bf, accB, 0, 0, 0);
        }
    }

    if (kq < 2) {
        #pragma unroll
        for (int r = 0; r < 4; ++r)
            out[(size_t)(pix0 + kq * 4 + r) * NF + w * 16 + m] = accB[r];
    }
}

extern "C" void kernel_launch(void* const* d_in, const int* in_sizes, int n_in,
                              void* d_out, int out_size, void* d_ws, size_t ws_size,
                              hipStream_t stream) {
    const float* xin  = (const float*)d_in[0];
    const float* offk = (const float*)d_in[1];
    const float* offb = (const float*)d_in[2];
    const float* wk   = (const float*)d_in[3];
    float* outp = (float*)d_out;

    _Float16* offkt = (_Float16*)((char*)d_ws + WS_OFFKT);
    _Float16* wkh   = (_Float16*)((char*)d_ws + WS_WK);

    dcn_prep<<<324, 256, 0, stream>>>(offk, wk, offkt, wkh);
    dcn_main<<<NPIX / PIXB, 256, 0, stream>>>(xin, offkt, offb, wkh, outp);
}

// Round 3
// 114.154 us; speedup vs baseline: 1.1447x; 1.1447x over previous
//
#include <hip/hip_runtime.h>

// DeformableConv2D round 7: round-4 structure (PIXB=16, 784 blocks) + explicit
// memory-level parallelism in phase B.
//
// Round-5/6 post-mortem: occupancy doubled (23.6->48.6%) with VALUBusy flat at
// ~23% and time WORSE (60.5->74.4us) -> the kernel is not wave-starved, it is
// starved of per-wave loads-in-flight. Compiler chose VGPR=40 regardless of
// launch bounds and kept only ~one p-iteration of gathers outstanding.
// Fix here: phase B processes 4 pixels per chunk with named register arrays --
// 8 broadcast LDS reads, then 16 independent global gathers issued together,
// then the FMA/pack stage. Fully unrolled, statically indexed. ~48 VGPR chunk
// working set under the (256,4) cap of 128 => compiler can overlap chunks too.
//
// prep: offset weights -> f16 transposed [80][576]; conv weights -> f16.
// main: 784 blocks x 256 thr (4 waves), 16 pixels/block.
//   A : offset conv as MFMA GEMM, A-frags gathered straight from global x.
//       Waves split the 5 N-tiles (wave 3 takes tiles 3 and 4). ZERO barriers.
//   A': coord/weight table, lane = sample (576 items / 256 thr).
//   B : per tap: 4 chunks x {8 LDS broadcast reads, 16 gathers, 4 wsum+pack}
//       -> s_sa[w], then 2 MFMAs. Wave w only touches s_sa[w] => NO barriers.
// Barriers per block: 2.
//
// MFMA 16x16x32 f16 layouts (verified by earlier passing runs):
//   A-frag: lane holds A[m=lane&15][k=(lane>>4)*8+j]
//   B-frag: lane holds B[k=(lane>>4)*8+j][n=lane&15]   (B stored [n][k])
//   C/D  : col(n)=lane&15, row(m)=(lane>>4)*4+reg

#define NH 56
#define NW 56
#define NC 64
#define NDG 4
#define NK 9
#define NOFF 72
#define NOFFP 80
#define NF 64
#define KTOT 576
#define HWPIX 3136
#define NPIX 12544

#define WS_OFFKT 0          // f16 [80][576]   = 92160 B
#define WS_WK    92160      // f16 [9][64][64] = 73728 B

typedef _Float16 half8   __attribute__((ext_vector_type(8)));
typedef float    floatx4 __attribute__((ext_vector_type(4)));

// ---------------- prep: weight conversion ----------------
__global__ __launch_bounds__(256)
void dcn_prep(const float* __restrict__ offk,   // [3,3,64,72] (kk,oc)
              const float* __restrict__ wk,     // [3,3,64,64] (k,f,c)
              _Float16* __restrict__ offkt,     // [80][576]   (oc,kk)
              _Float16* __restrict__ wkh)       // [9][64][64]
{
    const int i = blockIdx.x * 256 + threadIdx.x;
    if (i < NOFFP * KTOT) {
        const int oc = i / KTOT;
        const int kk = i - oc * KTOT;
        const float v = (oc < NOFF) ? offk[kk * NOFF + oc] : 0.0f;
        offkt[i] = (_Float16)v;
    }
    const int j = i - NOFFP * KTOT;
    if (j >= 0 && j < NK * NF * NC) wkh[j] = (_Float16)wk[j];
}

// ---------------- fused main ----------------
__global__ __launch_bounds__(256, 4)
void dcn_main(const float* __restrict__ x,        // [4,56,56,64]
              const _Float16* __restrict__ offkt, // [80][576]
              const float* __restrict__ offb,     // [72]
              const _Float16* __restrict__ wkh,   // [9][64][64]
              float* __restrict__ out)            // [12544][64]
{
    __shared__ float s_off[16 * NOFF];                    // 4.6 KB
    __shared__ __align__(16) float s_cww[576 * 4];        // 9.2 KB
    __shared__ __align__(16) int   s_cwi[576 * 4];        // 9.2 KB
    __shared__ __align__(16) _Float16 s_sa[4][16 * 72];   // 9.2 KB

    const int tid  = threadIdx.x;
    const int w    = tid >> 6;      // wave id: A = N-tile, B = group
    const int lane = tid & 63;
    const int m    = lane & 15;     // MFMA row / col index
    const int kq   = lane >> 4;     // MFMA k-quad

    const int pix0 = blockIdx.x * 16;
    const int pixm = pix0 + m;
    const int bm   = pixm / HWPIX;
    const int rrm  = pixm - bm * HWPIX;
    const int ohm  = rrm / NW;
    const int owm  = rrm - ohm * NW;
    const float* xbase = x + (size_t)(bm * HWPIX + ohm * NW + owm) * NC + kq * 8;

    // ---- phase A: offset conv GEMM, zero barriers ----
    const int oc0 = w * 16 + m;     // 0..63
    floatx4 acc0, acc1;
    { const float bv = offb[oc0]; acc0 = (floatx4){bv, bv, bv, bv}; }
    { const float bv = (w == 3 && m < 8) ? offb[64 + m] : 0.0f;
      acc1 = (floatx4){bv, bv, bv, bv}; }

    #pragma unroll
    for (int k = 0; k < NK; ++k) {
        const int ki = k / 3, kj = k - 3 * ki;
        const int ih = ohm + ki - 1, iw = owm + kj - 1;
        const bool vld = ((unsigned)ih < NH) && ((unsigned)iw < NW);
        const float* ap = xbase + ((ki - 1) * NW + (kj - 1)) * NC;
        #pragma unroll
        for (int s = 0; s < 2; ++s) {
            float4 a0 = make_float4(0.f, 0.f, 0.f, 0.f), a1 = a0;
            if (vld) {
                a0 = *(const float4*)(ap + s * 32);
                a1 = *(const float4*)(ap + s * 32 + 4);
            }
            half8 af;
            af[0] = (_Float16)a0.x; af[1] = (_Float16)a0.y;
            af[2] = (_Float16)a0.z; af[3] = (_Float16)a0.w;
            af[4] = (_Float16)a1.x; af[5] = (_Float16)a1.y;
            af[6] = (_Float16)a1.z; af[7] = (_Float16)a1.w;
            const int kkb = k * 64 + s * 32 + kq * 8;
            const half8 bf0 = *(const half8*)&offkt[(size_t)oc0 * KTOT + kkb];
            acc0 = __builtin_amdgcn_mfma_f32_16x16x32_f16(af, bf0, acc0, 0, 0, 0);
            if (w == 3) {
                const half8 bf1 = *(const half8*)&offkt[(size_t)(64 + m) * KTOT + kkb];
                acc1 = __builtin_amdgcn_mfma_f32_16x16x32_f16(af, bf1, acc1, 0, 0, 0);
            }
        }
    }
    #pragma unroll
    for (int r = 0; r < 4; ++r)
        s_off[(kq * 4 + r) * NOFF + oc0] = acc0[r];
    if (w == 3 && m < 8) {
        #pragma unroll
        for (int r = 0; r < 4; ++r)
            s_off[(kq * 4 + r) * NOFF + 64 + m] = acc1[r];
    }
    __syncthreads();

    // ---- phase A': coord/weight table, lane = sample ----
    for (int i = tid; i < 16 * 36; i += 256) {
        const int p  = i / 36;
        const int kg = i - p * 36;              // k*NDG + g
        const int k  = kg >> 2;
        const int ki = k / 3, kj = k - 3 * ki;
        const int pix = pix0 + p;
        const int b   = pix / HWPIX;
        const int rr  = pix - b * HWPIX;
        const int oh  = rr / NW, ow = rr - (rr / NW) * NW;
        const float offy = s_off[p * NOFF + kg * 2 + 0];
        const float offx = s_off[p * NOFF + kg * 2 + 1];
        float yv = fminf(fmaxf((float)(oh + ki) + offy, 0.0f), 57.0f);
        float xv = fminf(fmaxf((float)(ow + kj) + offx, 0.0f), 57.0f);
        const float y0f = floorf(yv), x0f = floorf(xv);
        const int y0 = (int)y0f, x0 = (int)x0f;
        const int y1 = min(y0 + 1, 57), x1 = min(x0 + 1, 57);
        const float ly = yv - y0f,       lx = xv - x0f;
        const float hy = (float)y1 - yv, hx = (float)x1 - xv;
        const bool vy0 = (unsigned)(y0 - 1) < NH;
        const bool vy1 = (unsigned)(y1 - 1) < NH;
        const bool vx0 = (unsigned)(x0 - 1) < NW;
        const bool vx1 = (unsigned)(x1 - 1) < NW;
        const float w00 = (vy0 && vx0) ? hy * hx : 0.0f;
        const float w01 = (vy0 && vx1) ? hy * lx : 0.0f;
        const float w10 = (vy1 && vx0) ? ly * hx : 0.0f;
        const float w11 = (vy1 && vx1) ? ly * lx : 0.0f;
        const int y0c = min(max(y0 - 1, 0), NH - 1);
        const int y1c = min(max(y1 - 1, 0), NH - 1);
        const int x0c = min(max(x0 - 1, 0), NW - 1);
        const int x1c = min(max(x1 - 1, 0), NW - 1);
        const int bb = b * HWPIX;
        *(float4*)&s_cww[i * 4] = make_float4(w00, w01, w10, w11);
        *(int4*)&s_cwi[i * 4]   = make_int4((bb + y0c * NW + x0c) * NC,
                                            (bb + y0c * NW + x1c) * NC,
                                            (bb + y1c * NW + x0c) * NC,
                                            (bb + y1c * NW + x1c) * NC);
    }
    __syncthreads();

    // ---- phase B: sampling + grouped conv, zero barriers ----
    floatx4 accB = (floatx4){0.f, 0.f, 0.f, 0.f};
    _Float16* sa = &s_sa[w][0];
    #pragma unroll 1
    for (int k = 0; k < NK; ++k) {
        // 4 chunks of 4 pixels: issue all 16 gathers of a chunk together so
        // the wave keeps >=16 loads in flight (was ~4 with the rolled form).
        #pragma unroll
        for (int c = 0; c < 4; ++c) {
            float4 cw[4]; int4 ci[4];
            #pragma unroll
            for (int q = 0; q < 4; ++q) {
                const int p = c * 4 + q;
                const int i = (p * 36 + k * 4 + w) * 4;
                cw[q] = *(const float4*)&s_cww[i];   // broadcast (uniform addr)
                ci[q] = *(const int4*)&s_cwi[i];
            }
            float g[4][4];
            #pragma unroll
            for (int q = 0; q < 4; ++q) {
                g[q][0] = x[ci[q].x + lane];
                g[q][1] = x[ci[q].y + lane];
                g[q][2] = x[ci[q].z + lane];
                g[q][3] = x[ci[q].w + lane];
            }
            #pragma unroll
            for (int q = 0; q < 4; ++q) {
                const int p = c * 4 + q;
                float v =       cw[q].x * g[q][0];
                v = fmaf(cw[q].y, g[q][1], v);
                v = fmaf(cw[q].z, g[q][2], v);
                v = fmaf(cw[q].w, g[q][3], v);
                sa[p * 72 + lane] = (_Float16)v;
            }
        }
        #pragma unroll
        for (int s = 0; s < 2; ++s) {
            const half8 af = *(const half8*)&sa[m * 72 + s * 32 + kq * 8];
            const half8 bf = *(const half8*)&wkh[(size_t)(k * NF + w * 16 + m) * NC +
                                                 s * 32 + kq * 8];
            accB = __builtin_amdgcn_mfma_f32_16x16x32_f16(af, bf, accB, 0, 0, 0);
        }
    }

    #pragma unroll
    for (int r = 0; r < 4; ++r)
        out[(size_t)(pix0 + kq * 4 + r) * NF + w * 16 + m] = accB[r];
}

extern "C" void kernel_launch(void* const* d_in, const int* in_sizes, int n_in,
                              void* d_out, int out_size, void* d_ws, size_t ws_size,
                              hipStream_t stream) {
    const float* xin  = (const float*)d_in[0];
    const float* offk = (const float*)d_in[1];
    const float* offb = (const float*)d_in[2];
    const float* wk   = (const float*)d_in[3];
    float* outp = (float*)d_out;

    _Float16* offkt = (_Float16*)((char*)d_ws + WS_OFFKT);
    _Float16* wkh   = (_Float16*)((char*)d_ws + WS_WK);

    dcn_prep<<<324, 256, 0, stream>>>(offk, wk, offkt, wkh);
    dcn_main<<<NPIX / 16, 256, 0, stream>>>(xin, offkt, offb, wkh, outp);
}